// Round 1
// baseline (1256.303 us; speedup 1.0000x reference)
//
#include <hip/hip_runtime.h>
#include <cmath>

#define B_SZ 1280
#define EDIM 512
#define DDIM 1024   // 2E
#define CDIM 3072   // 6E

// ---------------------------------------------------------------------------
// Kernel 1: mean over leading T axis of x[T, B, D] (optionally masked by lens)
// One block per batch row b; 256 threads each own a float4 of D=1024.
// Fully coalesced: for fixed t a block reads a contiguous 4 KB row.
// ---------------------------------------------------------------------------
__global__ __launch_bounds__(256) void mean_reduce_kernel(
    const float* __restrict__ x, const int* __restrict__ lens, int T,
    float* __restrict__ dst, int ldd, int coff)
{
    const int b  = blockIdx.x;
    const int d4 = threadIdx.x;  // 0..255
    const float4* xp = reinterpret_cast<const float4*>(x) + (size_t)b * (DDIM / 4) + d4;
    int len = T;
    if (lens) { len = lens[b]; if (len < 1) len = 1; }
    const size_t stride = (size_t)B_SZ * (DDIM / 4);
    float4 acc = make_float4(0.f, 0.f, 0.f, 0.f);
    for (int t = 0; t < len; ++t) {
        float4 v = xp[(size_t)t * stride];
        acc.x += v.x; acc.y += v.y; acc.z += v.z; acc.w += v.w;
    }
    const float inv = 1.0f / (float)len;
    acc.x *= inv; acc.y *= inv; acc.z *= inv; acc.w *= inv;
    float* o = dst + (size_t)b * ldd + coff + d4 * 4;
    *reinterpret_cast<float4*>(o) = acc;
}

// ---------------------------------------------------------------------------
// Kernel 2: fp32 GEMM  C[M,N] (+coff cols) = A[M,K] @ B[K,N] + bias, opt. ELU
// 64x64 tile, BK=16, 256 threads, 4x4 microtile. LDS stride 68 (=64+4):
// transpose-store of A is 2-way (free), float4 reads stay 16B aligned.
// M=1280, N=512 are exact multiples of the tile; K multiple of 16.
// ---------------------------------------------------------------------------
__global__ __launch_bounds__(256) void gemm_bias_kernel(
    const float* __restrict__ A, int lda,
    const float* __restrict__ Bw, int ldb,
    const float* __restrict__ bias,
    float* __restrict__ C, int ldc, int coff,
    int K, int elu)
{
    __shared__ __align__(16) float As[16][68];
    __shared__ __align__(16) float Bs[16][68];

    const int tid = threadIdx.x;
    const int tx  = tid & 15;        // micro-tile col group
    const int ty  = tid >> 4;        // micro-tile row group
    const int bx  = blockIdx.x;      // N / 64
    const int by  = blockIdx.y;      // M / 64

    const int arow = tid >> 2;          // 0..63
    const int acol = (tid & 3) << 2;    // 0,4,8,12
    const int brow = tid >> 4;          // 0..15
    const int bcol = (tid & 15) << 2;   // 0..60

    float acc[4][4] = {};

    const float* Aptr = A + (size_t)(by * 64 + arow) * lda + acol;
    const float* Bptr = Bw + (size_t)brow * ldb + bx * 64 + bcol;

    for (int k0 = 0; k0 < K; k0 += 16) {
        float4 a4 = *reinterpret_cast<const float4*>(Aptr + k0);
        float4 b4 = *reinterpret_cast<const float4*>(Bptr + (size_t)k0 * ldb);
        As[acol + 0][arow] = a4.x;
        As[acol + 1][arow] = a4.y;
        As[acol + 2][arow] = a4.z;
        As[acol + 3][arow] = a4.w;
        *reinterpret_cast<float4*>(&Bs[brow][bcol]) = b4;
        __syncthreads();
#pragma unroll
        for (int k = 0; k < 16; ++k) {
            float4 av = *reinterpret_cast<const float4*>(&As[k][ty * 4]);
            float4 bv = *reinterpret_cast<const float4*>(&Bs[k][tx * 4]);
            float am[4] = {av.x, av.y, av.z, av.w};
            float bn[4] = {bv.x, bv.y, bv.z, bv.w};
#pragma unroll
            for (int i = 0; i < 4; ++i)
#pragma unroll
                for (int j = 0; j < 4; ++j)
                    acc[i][j] = fmaf(am[i], bn[j], acc[i][j]);
        }
        __syncthreads();
    }

    const int n0 = bx * 64 + tx * 4;
    float4 bb = *reinterpret_cast<const float4*>(bias + n0);
#pragma unroll
    for (int i = 0; i < 4; ++i) {
        float4 c;
        c.x = acc[i][0] + bb.x;
        c.y = acc[i][1] + bb.y;
        c.z = acc[i][2] + bb.z;
        c.w = acc[i][3] + bb.w;
        if (elu) {
            c.x = c.x > 0.f ? c.x : expf(c.x) - 1.f;
            c.y = c.y > 0.f ? c.y : expf(c.y) - 1.f;
            c.z = c.z > 0.f ? c.z : expf(c.z) - 1.f;
            c.w = c.w > 0.f ? c.w : expf(c.w) - 1.f;
        }
        float* o = C + (size_t)(by * 64 + ty * 4 + i) * ldc + coff + n0;
        *reinterpret_cast<float4*>(o) = c;
    }
}

// ---------------------------------------------------------------------------
// Kernel 3: BatchNorm batch stats (biased) per channel. 512 threads total,
// each owns one channel; row loop is coalesced across threads.
// ---------------------------------------------------------------------------
__global__ __launch_bounds__(256) void bn_stats_kernel(
    const float* __restrict__ h, float* __restrict__ mu, float* __restrict__ rstd)
{
    const int c = blockIdx.x * blockDim.x + threadIdx.x;  // 0..511
    float s = 0.f, ss = 0.f;
    for (int b = 0; b < B_SZ; ++b) {
        float v = h[(size_t)b * EDIM + c];
        s += v; ss += v * v;
    }
    const float m   = s / (float)B_SZ;
    const float var = ss / (float)B_SZ - m * m;
    mu[c]   = m;
    rstd[c] = rsqrtf(var + 1e-5f);
}

// ---------------------------------------------------------------------------
// Kernel 4: out[b] = sum_c ((h[b,c]-mu)*rstd*gamma + beta) * Wc2[c] + bc2
// One block (512 threads = 8 waves) per batch row.
// ---------------------------------------------------------------------------
__global__ __launch_bounds__(512) void final_kernel(
    const float* __restrict__ h,
    const float* __restrict__ mu, const float* __restrict__ rstd,
    const float* __restrict__ gamma, const float* __restrict__ beta,
    const float* __restrict__ Wc2, const float* __restrict__ bc2,
    float* __restrict__ out)
{
    const int b = blockIdx.x;
    const int c = threadIdx.x;
    float v = ((h[(size_t)b * EDIM + c] - mu[c]) * rstd[c] * gamma[c] + beta[c]) * Wc2[c];
#pragma unroll
    for (int off = 32; off > 0; off >>= 1) v += __shfl_down(v, off);
    __shared__ float red[8];
    const int lane = c & 63, wv = c >> 6;
    if (lane == 0) red[wv] = v;
    __syncthreads();
    if (c < 8) {
        v = red[c];
#pragma unroll
        for (int off = 4; off > 0; off >>= 1) v += __shfl_down(v, off);
        if (c == 0) out[b] = v + bc2[0];
    }
}

// ---------------------------------------------------------------------------
extern "C" void kernel_launch(void* const* d_in, const int* in_sizes, int n_in,
                              void* d_out, int out_size, void* d_ws, size_t ws_size,
                              hipStream_t stream)
{
    const float* q_emb = (const float*)d_in[0];   // [64,1280,1024]
    const float* vqu   = (const float*)d_in[1];   // [64,1280,1024]
    const float* a_emb = (const float*)d_in[2];   // [32,1280,1024]
    const float* van   = (const float*)d_in[3];   // [64,1280,1024]
    const int*   qlen  = (const int*)d_in[4];
    const int*   alen  = (const int*)d_in[5];
    const float* Wq    = (const float*)d_in[6];   // [1024,512]
    const float* bq    = (const float*)d_in[7];
    const float* Wa    = (const float*)d_in[8];
    const float* ba    = (const float*)d_in[9];
    const float* Wc1   = (const float*)d_in[10];  // [3072,512]
    const float* bc1   = (const float*)d_in[11];
    const float* gamma = (const float*)d_in[12];
    const float* beta  = (const float*)d_in[13];
    const float* Wc2   = (const float*)d_in[14];  // [512,1]
    const float* bc2   = (const float*)d_in[15];
    float* out = (float*)d_out;

    float* ws     = (float*)d_ws;
    float* concat = ws;                               // [1280,3072]
    float* q_mean = concat + (size_t)B_SZ * CDIM;     // [1280,1024]
    float* a_mean = q_mean + (size_t)B_SZ * DDIM;     // [1280,1024]
    float* h      = a_mean + (size_t)B_SZ * DDIM;     // [1280,512]
    float* mu     = h + (size_t)B_SZ * EDIM;          // [512]
    float* rstd   = mu + EDIM;                        // [512]

    // Stage 1: means. vq/va land directly in the concat buffer.
    mean_reduce_kernel<<<B_SZ, 256, 0, stream>>>(q_emb, qlen,    64, q_mean, DDIM, 0);
    mean_reduce_kernel<<<B_SZ, 256, 0, stream>>>(vqu,   nullptr, 64, concat, CDIM, EDIM);
    mean_reduce_kernel<<<B_SZ, 256, 0, stream>>>(a_emb, alen,    32, a_mean, DDIM, 0);
    mean_reduce_kernel<<<B_SZ, 256, 0, stream>>>(van,   nullptr, 64, concat, CDIM, 4 * EDIM);

    // Stage 2: q = q_mean@Wq+bq, a = a_mean@Wa+ba (into concat cols), then
    //          h = elu(concat@Wc1 + bc1)
    dim3 g1(EDIM / 64, B_SZ / 64);  // (8, 20)
    gemm_bias_kernel<<<g1, 256, 0, stream>>>(q_mean, DDIM, Wq,  EDIM, bq,  concat, CDIM, 0,        DDIM, 0);
    gemm_bias_kernel<<<g1, 256, 0, stream>>>(a_mean, DDIM, Wa,  EDIM, ba,  concat, CDIM, 3 * EDIM, DDIM, 0);
    gemm_bias_kernel<<<g1, 256, 0, stream>>>(concat, CDIM, Wc1, EDIM, bc1, h,      EDIM, 0,        CDIM, 1);

    // Stage 3: BN stats + final projection
    bn_stats_kernel<<<2, 256, 0, stream>>>(h, mu, rstd);
    final_kernel<<<B_SZ, 512, 0, stream>>>(h, mu, rstd, gamma, beta, Wc2, bc2, out);
}